// Round 3
// baseline (177.976 us; speedup 1.0000x reference)
//
#include <hip/hip_runtime.h>
#include <hip/hip_bf16.h>

#define T_TOK 256
#define C_DIM 1024
#define H_DIM 2048
#define E_NUM 8

#define BM 16
#define BN 64
#define KC 256

typedef __attribute__((ext_vector_type(4))) float f32x4;
typedef __attribute__((ext_vector_type(8))) short short8;

// workspace layout (bytes)
#define WS_IDX   0
#define WS_CNT   1024
#define WS_LIST  2048                        // 8*256*4 = 8192
#define WS_HBUF  16384                       // 256*2048*2 = 1 MB (bf16)
#define WS_HSBUF (16384 + 1048576)           // 1 MB (bf16)
#define WS_YS    (16384 + 2*1048576)         // 1 MB (f32)

__device__ __forceinline__ ushort f2bf(float f) {
    __hip_bfloat16 h = __float2bfloat16(f);
    return *reinterpret_cast<ushort*>(&h);
}

__device__ __forceinline__ short8 pack8(float4 a, float4 b) {
    short8 s;
    s[0] = (short)f2bf(a.x); s[1] = (short)f2bf(a.y);
    s[2] = (short)f2bf(a.z); s[3] = (short)f2bf(a.w);
    s[4] = (short)f2bf(b.x); s[5] = (short)f2bf(b.y);
    s[6] = (short)f2bf(b.z); s[7] = (short)f2bf(b.w);
    return s;
}

__global__ __launch_bounds__(256) void router_kernel(
    const float* __restrict__ x, const float* __restrict__ router,
    int* __restrict__ idx, int* __restrict__ cnt, int* __restrict__ list)
{
    const int t = blockIdx.x;
    const int tid = threadIdx.x;
    float4 xv = reinterpret_cast<const float4*>(x + (size_t)t * C_DIM)[tid];
    float p[E_NUM];
#pragma unroll
    for (int e = 0; e < E_NUM; e++) {
        float4 rv = reinterpret_cast<const float4*>(router + (size_t)e * C_DIM)[tid];
        p[e] = xv.x * rv.x + xv.y * rv.y + xv.z * rv.z + xv.w * rv.w;
    }
#pragma unroll
    for (int e = 0; e < E_NUM; e++) {
#pragma unroll
        for (int off = 32; off >= 1; off >>= 1)
            p[e] += __shfl_down(p[e], off, 64);
    }
    __shared__ float red[E_NUM][4];
    const int lane = tid & 63, wv = tid >> 6;
    if (lane == 0) {
#pragma unroll
        for (int e = 0; e < E_NUM; e++) red[e][wv] = p[e];
    }
    __syncthreads();
    if (tid == 0) {
        float best = -3.4e38f; int bi = 0;
#pragma unroll
        for (int e = 0; e < E_NUM; e++) {
            float v = red[e][0] + red[e][1] + red[e][2] + red[e][3];
            if (v > best) { best = v; bi = e; }
        }
        idx[t] = bi;
        int pos = atomicAdd(&cnt[bi], 1);
        list[bi * T_TOK + pos] = t;
    }
}

// gathered bf16 MFMA GEMM: h[tok][hcol] = silu(x@gate^T) * (x@up^T)
// grid (9 experts [8=shared], H/BN, 16 token-tiles), block 256 (4 waves x 16 cols)
__global__ __launch_bounds__(256, 2) void ug_mfma(
    const float* __restrict__ x, const float* __restrict__ up, const float* __restrict__ gate,
    const float* __restrict__ w_up_s, const float* __restrict__ w_gate_s,
    const int* __restrict__ cnt, const int* __restrict__ list,
    ushort* __restrict__ hbuf, ushort* __restrict__ hsbuf)
{
    const int e = blockIdx.x;
    const bool sh = (e == E_NUM);
    const int n = sh ? T_TOK : cnt[e];
    const int tg0 = blockIdx.z * BM;
    if (tg0 >= n) return;

    const int tid = threadIdx.x;
    const int lane = tid & 63, wv = tid >> 6;

    __shared__ ushort As[BM][KC + 8];
    __shared__ int toks_s[BM];
    if (tid < BM) {
        int t = tg0 + tid;
        toks_s[tid] = (t < n) ? (sh ? t : list[e * T_TOK + t]) : -1;
    }
    __syncthreads();

    const int hglob = blockIdx.y * BN + wv * 16 + (lane & 15);
    const float* __restrict__ urow = sh ? (w_up_s   + (size_t)hglob * C_DIM)
                                        : (up   + ((size_t)e * H_DIM + hglob) * C_DIM);
    const float* __restrict__ grow = sh ? (w_gate_s + (size_t)hglob * C_DIM)
                                        : (gate + ((size_t)e * H_DIM + hglob) * C_DIM);
    const int klane = (lane >> 4) * 8;

    f32x4 accu = {0,0,0,0}, accg = {0,0,0,0};

    const int sr = tid & 15;          // staging row
    const int sc = (tid >> 4) * 16;   // staging col base (16 f32 per thread)
    const int stok = toks_s[sr];
    const float* xr = (stok >= 0) ? (x + (size_t)stok * C_DIM + sc) : x;

    float4 u0[2], u1[2], g0v[2], g1v[2];
#define LDW(slot, k0) do { \
        const float* pu_ = urow + kc + (k0) * 32 + klane; \
        const float* pg_ = grow + kc + (k0) * 32 + klane; \
        u0[slot]  = *reinterpret_cast<const float4*>(pu_); \
        u1[slot]  = *reinterpret_cast<const float4*>(pu_ + 4); \
        g0v[slot] = *reinterpret_cast<const float4*>(pg_); \
        g1v[slot] = *reinterpret_cast<const float4*>(pg_ + 4); \
    } while (0)

    for (int kc = 0; kc < C_DIM; kc += KC) {
        __syncthreads();
        {
            float4 a0 = {0,0,0,0}, a1 = {0,0,0,0}, a2 = {0,0,0,0}, a3 = {0,0,0,0};
            if (stok >= 0) {
                a0 = *reinterpret_cast<const float4*>(xr + kc);
                a1 = *reinterpret_cast<const float4*>(xr + kc + 4);
                a2 = *reinterpret_cast<const float4*>(xr + kc + 8);
                a3 = *reinterpret_cast<const float4*>(xr + kc + 12);
            }
            *reinterpret_cast<short8*>(&As[sr][sc])     = pack8(a0, a1);
            *reinterpret_cast<short8*>(&As[sr][sc + 8]) = pack8(a2, a3);
        }
        __syncthreads();

        const ushort* A0 = &As[lane & 15][klane];
        LDW(0, 0);
#pragma unroll
        for (int k0i = 0; k0i < 8; k0i++) {
            const int cur = k0i & 1, nxt = cur ^ 1;
            if (k0i < 7) LDW(nxt, k0i + 1);
            short8 a = *reinterpret_cast<const short8*>(A0 + k0i * 32);
            accu = __builtin_amdgcn_mfma_f32_16x16x32_bf16(a, pack8(u0[cur],  u1[cur]),  accu, 0, 0, 0);
            accg = __builtin_amdgcn_mfma_f32_16x16x32_bf16(a, pack8(g0v[cur], g1v[cur]), accg, 0, 0, 0);
        }
    }
#undef LDW

    ushort* __restrict__ outp = sh ? hsbuf : hbuf;
#pragma unroll
    for (int r = 0; r < 4; r++) {
        int m = (lane >> 4) * 4 + r;
        int tok = toks_s[m];
        if (tok >= 0) {
            float g = accg[r], u = accu[r];
            float hv = u * (g / (1.f + __expf(-g)));
            outp[(size_t)tok * H_DIM + hglob] = f2bf(hv);
        }
    }
}

// gathered bf16 MFMA GEMM: y[tok][c] = h @ down^T
// grid (9 experts [8=shared], C/BN, 16 token-tiles), block 256 (4 waves x 16 cols)
__global__ __launch_bounds__(256, 2) void down_mfma(
    const float* __restrict__ dwn, const float* __restrict__ w_down_s,
    const ushort* __restrict__ hbuf, const ushort* __restrict__ hsbuf,
    const int* __restrict__ cnt, const int* __restrict__ list,
    float* __restrict__ y, float* __restrict__ ysbuf)
{
    const int e = blockIdx.x;
    const bool sh = (e == E_NUM);
    const int n = sh ? T_TOK : cnt[e];
    const int tg0 = blockIdx.z * BM;
    if (tg0 >= n) return;

    const int tid = threadIdx.x;
    const int lane = tid & 63, wv = tid >> 6;

    __shared__ ushort Hs[BM][KC + 8];
    __shared__ int toks_s[BM];
    if (tid < BM) {
        int t = tg0 + tid;
        toks_s[tid] = (t < n) ? (sh ? t : list[e * T_TOK + t]) : -1;
    }
    __syncthreads();

    const int cglob = blockIdx.y * BN + wv * 16 + (lane & 15);
    const float* __restrict__ drow = sh ? (w_down_s + (size_t)cglob * H_DIM)
                                        : (dwn + ((size_t)e * C_DIM + cglob) * H_DIM);
    const int klane = (lane >> 4) * 8;
    const ushort* __restrict__ hin = sh ? hsbuf : hbuf;

    f32x4 acc = {0,0,0,0};

    const int sr = tid & 15;
    const int sc = (tid >> 4) * 16;
    const int stok = toks_s[sr];
    const ushort* hr = (stok >= 0) ? (hin + (size_t)stok * H_DIM + sc) : hin;

    float4 d0[3], d1[3];
#define LDD(slot, k0) do { \
        const float* pd_ = drow + kc + (k0) * 32 + klane; \
        d0[slot] = *reinterpret_cast<const float4*>(pd_); \
        d1[slot] = *reinterpret_cast<const float4*>(pd_ + 4); \
    } while (0)

    for (int kc = 0; kc < H_DIM; kc += KC) {
        __syncthreads();
        {
            short8 s0 = {0,0,0,0,0,0,0,0}, s1 = {0,0,0,0,0,0,0,0};
            if (stok >= 0) {
                s0 = *reinterpret_cast<const short8*>(hr + kc);
                s1 = *reinterpret_cast<const short8*>(hr + kc + 8);
            }
            *reinterpret_cast<short8*>(&Hs[sr][sc])     = s0;
            *reinterpret_cast<short8*>(&Hs[sr][sc + 8]) = s1;
        }
        __syncthreads();

        const ushort* A0 = &Hs[lane & 15][klane];
        LDD(0, 0);
        LDD(1, 1);
#pragma unroll
        for (int k0i = 0; k0i < 8; k0i++) {
            const int cur = k0i % 3;
            if (k0i < 6) LDD((k0i + 2) % 3, k0i + 2);
            short8 a = *reinterpret_cast<const short8*>(A0 + k0i * 32);
            acc = __builtin_amdgcn_mfma_f32_16x16x32_bf16(a, pack8(d0[cur], d1[cur]), acc, 0, 0, 0);
        }
    }
#undef LDD

    float* __restrict__ outp = sh ? ysbuf : y;
#pragma unroll
    for (int r = 0; r < 4; r++) {
        int m = (lane >> 4) * 4 + r;
        int tok = toks_s[m];
        if (tok >= 0) outp[(size_t)tok * C_DIM + cglob] = acc[r];
    }
}

__global__ __launch_bounds__(256) void add_kernel(float* __restrict__ y, const float* __restrict__ ys)
{
    int i = blockIdx.x * 256 + threadIdx.x;
    float4 a = reinterpret_cast<float4*>(y)[i];
    float4 b = reinterpret_cast<const float4*>(ys)[i];
    a.x += b.x; a.y += b.y; a.z += b.z; a.w += b.w;
    reinterpret_cast<float4*>(y)[i] = a;
}

extern "C" void kernel_launch(void* const* d_in, const int* in_sizes, int n_in,
                              void* d_out, int out_size, void* d_ws, size_t ws_size,
                              hipStream_t stream)
{
    const float* x        = (const float*)d_in[0];
    const float* up       = (const float*)d_in[1];
    const float* gate     = (const float*)d_in[2];
    const float* dwn      = (const float*)d_in[3];
    const float* router   = (const float*)d_in[4];
    const float* w_up_s   = (const float*)d_in[5];
    const float* w_gate_s = (const float*)d_in[6];
    const float* w_down_s = (const float*)d_in[7];

    char* ws = (char*)d_ws;
    int* idx     = (int*)(ws + WS_IDX);
    int* cnt     = (int*)(ws + WS_CNT);
    int* list    = (int*)(ws + WS_LIST);
    ushort* hbuf  = (ushort*)(ws + WS_HBUF);
    ushort* hsbuf = (ushort*)(ws + WS_HSBUF);
    float* ysbuf  = (float*)(ws + WS_YS);
    float* y = (float*)d_out;

    hipMemsetAsync(cnt, 0, E_NUM * sizeof(int), stream);
    router_kernel<<<T_TOK, 256, 0, stream>>>(x, router, idx, cnt, list);
    ug_mfma<<<dim3(E_NUM + 1, H_DIM / BN, T_TOK / BM), 256, 0, stream>>>(
        x, up, gate, w_up_s, w_gate_s, cnt, list, hbuf, hsbuf);
    down_mfma<<<dim3(E_NUM + 1, C_DIM / BN, T_TOK / BM), 256, 0, stream>>>(
        dwn, w_down_s, hbuf, hsbuf, cnt, list, y, ysbuf);
    add_kernel<<<(T_TOK * C_DIM / 4) / 256, 256, 0, stream>>>(y, ysbuf);
}

// Round 4
// 101.497 us; speedup vs baseline: 1.7535x; 1.7535x over previous
//
#include <hip/hip_runtime.h>
#include <hip/hip_bf16.h>

#define T_TOK 256
#define C_DIM 1024
#define H_DIM 2048
#define E_NUM 8
#define BN 64

typedef __attribute__((ext_vector_type(4))) float f32x4;
typedef __attribute__((ext_vector_type(8))) short short8;

// workspace layout (bytes)
#define WS_IDX   0
#define WS_CNT   1024
#define WS_LIST  2048                        // 8*256*4 = 8192
#define WS_HBUF  16384                       // 256*2048*2 = 1 MB (bf16)
#define WS_HSBUF (16384 + 1048576)           // 1 MB (bf16)
#define WS_YS    (16384 + 2*1048576)         // 1 MB (f32)

__device__ __forceinline__ ushort f2bf(float f) {
    __hip_bfloat16 h = __float2bfloat16(f);
    return *reinterpret_cast<ushort*>(&h);
}

__device__ __forceinline__ short8 pack8(float4 a, float4 b) {
    short8 s;
    s[0] = (short)f2bf(a.x); s[1] = (short)f2bf(a.y);
    s[2] = (short)f2bf(a.z); s[3] = (short)f2bf(a.w);
    s[4] = (short)f2bf(b.x); s[5] = (short)f2bf(b.y);
    s[6] = (short)f2bf(b.z); s[7] = (short)f2bf(b.w);
    return s;
}

__global__ __launch_bounds__(256) void router_kernel(
    const float* __restrict__ x, const float* __restrict__ router,
    int* __restrict__ idx, int* __restrict__ cnt, int* __restrict__ list)
{
    const int t = blockIdx.x;
    const int tid = threadIdx.x;
    float4 xv = reinterpret_cast<const float4*>(x + (size_t)t * C_DIM)[tid];
    float p[E_NUM];
#pragma unroll
    for (int e = 0; e < E_NUM; e++) {
        float4 rv = reinterpret_cast<const float4*>(router + (size_t)e * C_DIM)[tid];
        p[e] = xv.x * rv.x + xv.y * rv.y + xv.z * rv.z + xv.w * rv.w;
    }
#pragma unroll
    for (int e = 0; e < E_NUM; e++) {
#pragma unroll
        for (int off = 32; off >= 1; off >>= 1)
            p[e] += __shfl_down(p[e], off, 64);
    }
    __shared__ float red[E_NUM][4];
    const int lane = tid & 63, wv = tid >> 6;
    if (lane == 0) {
#pragma unroll
        for (int e = 0; e < E_NUM; e++) red[e][wv] = p[e];
    }
    __syncthreads();
    if (tid == 0) {
        float best = -3.4e38f; int bi = 0;
#pragma unroll
        for (int e = 0; e < E_NUM; e++) {
            float v = red[e][0] + red[e][1] + red[e][2] + red[e][3];
            if (v > best) { best = v; bi = e; }
        }
        idx[t] = bi;
        int pos = atomicAdd(&cnt[bi], 1);
        list[bi * T_TOK + pos] = t;
    }
}

// gathered bf16 MFMA GEMM: h[tok][hcol] = silu(x@gate^T) * (x@up^T)
// BM=64 (4 m-frags), BN=64, KCW=64, K=1024 -> 16 tiles.
// grid (9 experts [8=shared], H/64=32, 4 token-tiles), block 256 (4 waves)
__global__ __launch_bounds__(256, 3) void ug_mfma(
    const float* __restrict__ x, const float* __restrict__ up, const float* __restrict__ gate,
    const float* __restrict__ w_up_s, const float* __restrict__ w_gate_s,
    const int* __restrict__ cnt, const int* __restrict__ list,
    ushort* __restrict__ hbuf, ushort* __restrict__ hsbuf)
{
    const int e = blockIdx.x;
    const bool sh = (e == E_NUM);
    const int n = sh ? T_TOK : cnt[e];
    const int tg0 = blockIdx.z * 64;
    if (tg0 >= n) return;

    const int tid = threadIdx.x;
    const int lane = tid & 63, wv = tid >> 6;

    __shared__ ushort Ax[64][72];
    __shared__ ushort Wu[64][72];
    __shared__ ushort Wg[64][72];
    __shared__ int toks_s[64];
    if (tid < 64) {
        int t = tg0 + tid;
        toks_s[tid] = (t < n) ? (sh ? t : list[e * T_TOK + t]) : -1;
    }
    __syncthreads();

    // staging: thread -> row (t>>2 of 64), 16 consecutive f32 at seg (t&3)*16
    const int srow = tid >> 2;
    const int sseg = (tid & 3) * 16;
    const float* __restrict__ pu = (sh ? w_up_s   : up   + (size_t)e * H_DIM * C_DIM)
                                   + (size_t)(blockIdx.y * BN + srow) * C_DIM + sseg;
    const float* __restrict__ pg = (sh ? w_gate_s : gate + (size_t)e * H_DIM * C_DIM)
                                   + (size_t)(blockIdx.y * BN + srow) * C_DIM + sseg;
    const int stok = toks_s[srow];
    const float* __restrict__ px = x + (size_t)(stok < 0 ? 0 : stok) * C_DIM + sseg;

    float4 ru[4], rg[4], rx[4];
#define UG_LOAD(kc) do { \
        _Pragma("unroll") \
        for (int i = 0; i < 4; i++) { \
            ru[i] = *reinterpret_cast<const float4*>(pu + (kc) + i * 4); \
            rg[i] = *reinterpret_cast<const float4*>(pg + (kc) + i * 4); \
            rx[i] = (stok >= 0) ? *reinterpret_cast<const float4*>(px + (kc) + i * 4) \
                                : float4{0.f, 0.f, 0.f, 0.f}; \
        } \
    } while (0)

    const int klane = (lane >> 4) * 8;
    const int mrow = lane & 15;
    f32x4 au[4] = {{0,0,0,0},{0,0,0,0},{0,0,0,0},{0,0,0,0}};
    f32x4 ag[4] = {{0,0,0,0},{0,0,0,0},{0,0,0,0},{0,0,0,0}};

    UG_LOAD(0);
#pragma unroll 1
    for (int t = 0; t < 16; t++) {
        __syncthreads();
        *reinterpret_cast<short8*>(&Wu[srow][sseg])     = pack8(ru[0], ru[1]);
        *reinterpret_cast<short8*>(&Wu[srow][sseg + 8]) = pack8(ru[2], ru[3]);
        *reinterpret_cast<short8*>(&Wg[srow][sseg])     = pack8(rg[0], rg[1]);
        *reinterpret_cast<short8*>(&Wg[srow][sseg + 8]) = pack8(rg[2], rg[3]);
        *reinterpret_cast<short8*>(&Ax[srow][sseg])     = pack8(rx[0], rx[1]);
        *reinterpret_cast<short8*>(&Ax[srow][sseg + 8]) = pack8(rx[2], rx[3]);
        __syncthreads();
        if (t < 15) UG_LOAD((t + 1) * 64);
#pragma unroll
        for (int k0 = 0; k0 < 64; k0 += 32) {
            short8 bu = *reinterpret_cast<const short8*>(&Wu[wv * 16 + mrow][klane + k0]);
            short8 bg = *reinterpret_cast<const short8*>(&Wg[wv * 16 + mrow][klane + k0]);
#pragma unroll
            for (int mf = 0; mf < 4; mf++) {
                short8 a = *reinterpret_cast<const short8*>(&Ax[mf * 16 + mrow][klane + k0]);
                au[mf] = __builtin_amdgcn_mfma_f32_16x16x32_bf16(a, bu, au[mf], 0, 0, 0);
                ag[mf] = __builtin_amdgcn_mfma_f32_16x16x32_bf16(a, bg, ag[mf], 0, 0, 0);
            }
        }
    }
#undef UG_LOAD

    const int hglob = blockIdx.y * BN + wv * 16 + mrow;
    ushort* __restrict__ outp = sh ? hsbuf : hbuf;
#pragma unroll
    for (int mf = 0; mf < 4; mf++) {
#pragma unroll
        for (int r = 0; r < 4; r++) {
            int m = mf * 16 + (lane >> 4) * 4 + r;
            int tok = toks_s[m];
            if (tok >= 0) {
                float g = ag[mf][r], u = au[mf][r];
                float hv = u * (g / (1.f + __expf(-g)));
                outp[(size_t)tok * H_DIM + hglob] = f2bf(hv);
            }
        }
    }
}

// gathered bf16 MFMA GEMM: y[tok][c] = h @ down^T
// BM=32 (2 m-frags), BN=64, KCW=64, K=2048 -> 32 tiles.
// grid (9 experts [8=shared], C/64=16, 8 token-tiles), block 256 (4 waves)
__global__ __launch_bounds__(256, 4) void down_mfma(
    const float* __restrict__ dwn, const float* __restrict__ w_down_s,
    const ushort* __restrict__ hbuf, const ushort* __restrict__ hsbuf,
    const int* __restrict__ cnt, const int* __restrict__ list,
    float* __restrict__ y, float* __restrict__ ysbuf)
{
    const int e = blockIdx.x;
    const bool sh = (e == E_NUM);
    const int n = sh ? T_TOK : cnt[e];
    const int tg0 = blockIdx.z * 32;
    if (tg0 >= n) return;

    const int tid = threadIdx.x;
    const int lane = tid & 63, wv = tid >> 6;

    __shared__ ushort Ah[32][72];
    __shared__ ushort Wd[64][72];
    __shared__ int toks_s[32];
    if (tid < 32) {
        int t = tg0 + tid;
        toks_s[tid] = (t < n) ? (sh ? t : list[e * T_TOK + t]) : -1;
    }
    __syncthreads();

    const int srow = tid >> 2;          // weight row 0..63
    const int sseg = (tid & 3) * 16;
    const float* __restrict__ pd = (sh ? w_down_s : dwn + (size_t)e * C_DIM * H_DIM)
                                   + (size_t)(blockIdx.y * BN + srow) * H_DIM + sseg;
    const int hrow = tid >> 3;          // h row 0..31
    const int hseg = (tid & 7) * 8;     // 8 bf16 = 16B
    const int stok = toks_s[hrow];
    const ushort* __restrict__ hin = sh ? hsbuf : hbuf;
    const ushort* __restrict__ ph = hin + (size_t)(stok < 0 ? 0 : stok) * H_DIM + hseg;

    float4 rd[4]; short8 rh;
#define DN_LOAD(kc) do { \
        _Pragma("unroll") \
        for (int i = 0; i < 4; i++) \
            rd[i] = *reinterpret_cast<const float4*>(pd + (kc) + i * 4); \
        rh = (stok >= 0) ? *reinterpret_cast<const short8*>(ph + (kc)) \
                         : short8{0,0,0,0,0,0,0,0}; \
    } while (0)

    const int klane = (lane >> 4) * 8;
    const int mrow = lane & 15;
    f32x4 acc[2] = {{0,0,0,0},{0,0,0,0}};

    DN_LOAD(0);
#pragma unroll 1
    for (int t = 0; t < 32; t++) {
        __syncthreads();
        *reinterpret_cast<short8*>(&Wd[srow][sseg])     = pack8(rd[0], rd[1]);
        *reinterpret_cast<short8*>(&Wd[srow][sseg + 8]) = pack8(rd[2], rd[3]);
        *reinterpret_cast<short8*>(&Ah[hrow][hseg])     = rh;
        __syncthreads();
        if (t < 31) DN_LOAD((t + 1) * 64);
#pragma unroll
        for (int k0 = 0; k0 < 64; k0 += 32) {
            short8 bd = *reinterpret_cast<const short8*>(&Wd[wv * 16 + mrow][klane + k0]);
#pragma unroll
            for (int mf = 0; mf < 2; mf++) {
                short8 a = *reinterpret_cast<const short8*>(&Ah[mf * 16 + mrow][klane + k0]);
                acc[mf] = __builtin_amdgcn_mfma_f32_16x16x32_bf16(a, bd, acc[mf], 0, 0, 0);
            }
        }
    }
#undef DN_LOAD

    const int cglob = blockIdx.y * BN + wv * 16 + mrow;
    float* __restrict__ outp = sh ? ysbuf : y;
#pragma unroll
    for (int mf = 0; mf < 2; mf++) {
#pragma unroll
        for (int r = 0; r < 4; r++) {
            int m = mf * 16 + (lane >> 4) * 4 + r;
            int tok = toks_s[m];
            if (tok >= 0) outp[(size_t)tok * C_DIM + cglob] = acc[mf][r];
        }
    }
}

__global__ __launch_bounds__(256) void add_kernel(float* __restrict__ y, const float* __restrict__ ys)
{
    int i = blockIdx.x * 256 + threadIdx.x;
    float4 a = reinterpret_cast<float4*>(y)[i];
    float4 b = reinterpret_cast<const float4*>(ys)[i];
    a.x += b.x; a.y += b.y; a.z += b.z; a.w += b.w;
    reinterpret_cast<float4*>(y)[i] = a;
}

extern "C" void kernel_launch(void* const* d_in, const int* in_sizes, int n_in,
                              void* d_out, int out_size, void* d_ws, size_t ws_size,
                              hipStream_t stream)
{
    const float* x        = (const float*)d_in[0];
    const float* up       = (const float*)d_in[1];
    const float* gate     = (const float*)d_in[2];
    const float* dwn      = (const float*)d_in[3];
    const float* router   = (const float*)d_in[4];
    const float* w_up_s   = (const float*)d_in[5];
    const float* w_gate_s = (const float*)d_in[6];
    const float* w_down_s = (const float*)d_in[7];

    char* ws = (char*)d_ws;
    int* idx     = (int*)(ws + WS_IDX);
    int* cnt     = (int*)(ws + WS_CNT);
    int* list    = (int*)(ws + WS_LIST);
    ushort* hbuf  = (ushort*)(ws + WS_HBUF);
    ushort* hsbuf = (ushort*)(ws + WS_HSBUF);
    float* ysbuf  = (float*)(ws + WS_YS);
    float* y = (float*)d_out;

    hipMemsetAsync(cnt, 0, E_NUM * sizeof(int), stream);
    router_kernel<<<T_TOK, 256, 0, stream>>>(x, router, idx, cnt, list);
    ug_mfma<<<dim3(E_NUM + 1, H_DIM / BN, 4), 256, 0, stream>>>(
        x, up, gate, w_up_s, w_gate_s, cnt, list, hbuf, hsbuf);
    down_mfma<<<dim3(E_NUM + 1, C_DIM / BN, 8), 256, 0, stream>>>(
        dwn, w_down_s, hbuf, hsbuf, cnt, list, y, ysbuf);
    add_kernel<<<(T_TOK * C_DIM / 4) / 256, 256, 0, stream>>>(y, ysbuf);
}